// Round 5
// baseline (420.675 us; speedup 1.0000x reference)
//
#include <hip/hip_runtime.h>
#include <hip/hip_bf16.h>

#define B_    4
#define N_    8192
#define TOT   (B_*N_)      // 32768 points
#define KNN_  16
#define PPW   8            // points per wave in k2
#define PITCH 68           // k1 LDS tile pitch (conflict-free for b16 C-writes)

typedef _Float16 half8  __attribute__((ext_vector_type(8)));
typedef _Float16 half4  __attribute__((ext_vector_type(4)));
typedef __fp16   fp16x2 __attribute__((ext_vector_type(2)));
typedef float    floatx4 __attribute__((ext_vector_type(4)));

#define MFMA16(A, Bv, C) __builtin_amdgcn_mfma_f32_16x16x32_f16((A), (Bv), (C), 0, 0, 0)

__device__ __forceinline__ void lds_fence(){
  asm volatile("s_waitcnt lgkmcnt(0)" ::: "memory");
}
__device__ __forceinline__ half8 h8_load_f32(const float* __restrict__ p){
  float4 a = *(const float4*)p;
  float4 b = *(const float4*)(p + 4);
  half8 r;
  r[0] = (_Float16)a.x; r[1] = (_Float16)a.y; r[2] = (_Float16)a.z; r[3] = (_Float16)a.w;
  r[4] = (_Float16)b.x; r[5] = (_Float16)b.y; r[6] = (_Float16)b.z; r[7] = (_Float16)b.w;
  return r;
}
// pack two f32 -> one int of 2 f16 (RTZ)
__device__ __forceinline__ int pk2f(float a, float b){
  union { fp16x2 h; int i; } u;
  u.h = __builtin_amdgcn_cvt_pkrtz(a, b);
  return u.i;
}
// read 8 halfs from 8B-aligned LDS (k1 tile)
__device__ __forceinline__ half8 tile_read8(const _Float16* t, int idx){
  half4 lo = *(const half4*)(t + idx);
  half4 hi = *(const half4*)(t + idx + 4);
  half8 r;
  #pragma unroll
  for (int j = 0; j < 4; j++){ r[j] = lo[j]; r[4+j] = hi[j]; }
  return r;
}
// B-fragment of 64x64 row-major f32 weight direct from global (k3)
__device__ __forceinline__ half8 wfrag(const float* __restrict__ W, int kb, int n){
  half8 v;
  #pragma unroll
  for (int j = 0; j < 8; j++) v[j] = (_Float16)W[(kb + j)*64 + n];
  return v;
}
// LDS B-frag staging (k1, k2-g2): [(kt*4+nt)*64+lane] holds W[kt*32+q*8+j][nt*16+m16]
__device__ void fill_w64(half8* dst, const float* __restrict__ W, int tid){
  for (int i = tid; i < 512; i += 256){
    int lane = i & 63, nt = (i >> 6) & 3, kt = i >> 8;
    int n  = nt*16 + (lane & 15);
    int kb = kt*32 + ((lane >> 4) & 3)*8;
    half8 v;
    #pragma unroll
    for (int j = 0; j < 8; j++) v[j] = (_Float16)W[(kb + j)*64 + n];
    dst[i] = v;
  }
}

// quad-regroup: transposed-stage D-layout (packed) -> operand frag.
// pk[mt][h] = f16 pair of Y[16mt+4q+2h .. +1][m16]; out G[kt][j] = Y[32kt+8q+j][m16]
__device__ __forceinline__ void regroup(const int pk[4][2], half8 G[2], int ia, int ib, int sel){
  int a0h0 = __shfl(pk[0][0], ia, 64), a0h1 = __shfl(pk[0][1], ia, 64);
  int a1h0 = __shfl(pk[1][0], ia, 64), a1h1 = __shfl(pk[1][1], ia, 64);
  int a2h0 = __shfl(pk[2][0], ia, 64), a2h1 = __shfl(pk[2][1], ia, 64);
  int a3h0 = __shfl(pk[3][0], ia, 64), a3h1 = __shfl(pk[3][1], ia, 64);
  int b0h0 = __shfl(pk[0][0], ib, 64), b0h1 = __shfl(pk[0][1], ib, 64);
  int b1h0 = __shfl(pk[1][0], ib, 64), b1h1 = __shfl(pk[1][1], ib, 64);
  int b2h0 = __shfl(pk[2][0], ib, 64), b2h1 = __shfl(pk[2][1], ib, 64);
  int b3h0 = __shfl(pk[3][0], ib, 64), b3h1 = __shfl(pk[3][1], ib, 64);
  union { half8 h; int i[4]; } g0, g1;
  g0.i[0] = sel ? a1h0 : a0h0;
  g0.i[1] = sel ? a1h1 : a0h1;
  g0.i[2] = sel ? b1h0 : b0h0;
  g0.i[3] = sel ? b1h1 : b0h1;
  g1.i[0] = sel ? a3h0 : a2h0;
  g1.i[1] = sel ? a3h1 : a2h1;
  g1.i[2] = sel ? b3h0 : b2h0;
  g1.i[3] = sel ? b3h1 : b2h1;
  G[0] = g0.h; G[1] = g1.h;
}

// ---------------- kernel 1: x = fc1(features); q/xk/xv = x @ {wq,wk,wv} ----------------
__global__ __launch_bounds__(256, 2) void k1_qkv(
    const float* __restrict__ feat, const float* __restrict__ fc1w, const float* __restrict__ fc1b,
    const float* __restrict__ wqw, const float* __restrict__ wkw, const float* __restrict__ wvw,
    _Float16* __restrict__ qws, _Float16* __restrict__ kws, _Float16* __restrict__ vws)
{
  __shared__ half8 Sfc1[512], Sq[512], Sk[512], Sv[512];
  __shared__ alignas(16) _Float16 xt[4][16*PITCH];
  const int tid = threadIdx.x;
  fill_w64(Sfc1, fc1w, tid);
  fill_w64(Sq, wqw, tid);
  fill_w64(Sk, wkw, tid);
  fill_w64(Sv, wvw, tid);
  __syncthreads();

  const int wave = tid >> 6, lane = tid & 63, quad = lane >> 4, m16 = lane & 15;
  _Float16* tx = &xt[wave][0];
  const int rowbase = blockIdx.x*64 + wave*16;
  float fb[4];
  #pragma unroll
  for (int nt = 0; nt < 4; nt++) fb[nt] = fc1b[nt*16 + m16];

  const int arow = rowbase + m16;
  half8 Fa0 = h8_load_f32(&feat[arow*64 + quad*8]);
  half8 Fa1 = h8_load_f32(&feat[arow*64 + 32 + quad*8]);
  const floatx4 z4 = {0.f, 0.f, 0.f, 0.f};

  #pragma unroll
  for (int nt = 0; nt < 4; nt++){
    floatx4 acc = MFMA16(Fa0, Sfc1[nt*64 + lane], z4);
    acc = MFMA16(Fa1, Sfc1[(4 + nt)*64 + lane], acc);
    const int col = nt*16 + m16;
    #pragma unroll
    for (int r = 0; r < 4; r++)
      tx[(quad*4 + r)*PITCH + col] = (_Float16)(acc[r] + fb[nt]);
  }
  lds_fence();
  const half8 Ax0 = tile_read8(tx, m16*PITCH + quad*8);
  const half8 Ax1 = tile_read8(tx, m16*PITCH + 32 + quad*8);

#define EMIT_QKV(S, OUT)                                                      \
  { _Pragma("unroll")                                                         \
    for (int nt = 0; nt < 4; nt++){                                           \
      floatx4 acc = MFMA16(Ax0, S[nt*64 + lane], z4);                         \
      acc = MFMA16(Ax1, S[(4 + nt)*64 + lane], acc);                          \
      _Pragma("unroll")                                                       \
      for (int r = 0; r < 4; r++)                                             \
        OUT[(rowbase + quad*4 + r)*64 + nt*16 + m16] = (_Float16)acc[r];      \
    } }
  EMIT_QKV(Sq, qws)
  EMIT_QKV(Sk, kws)
  EMIT_QKV(Sv, vws)
#undef EMIT_QKV
}

// ---------------- kernel 2: fused pos_enc / attention, LDS-tile-free ----------------
__global__ __launch_bounds__(256, 3) void k2_point(
    const float* __restrict__ xyz, const int* __restrict__ knn,
    const float* __restrict__ d1w, const float* __restrict__ d1b,
    const float* __restrict__ d2w, const float* __restrict__ d2b,
    const float* __restrict__ g1w, const float* __restrict__ g1b,
    const float* __restrict__ g2w, const float* __restrict__ g2b,
    const _Float16* __restrict__ qws, const _Float16* __restrict__ kws,
    const _Float16* __restrict__ vws,
    _Float16* __restrict__ r0, float* __restrict__ attn_out)
{
  // Weight fragments in LDS (read-only after fill, no fences in the loop):
  __shared__ half8 SAd1[256];    // [mt*64+lane]: A-frag of d1^T, bias row at k=3
  __shared__ half8 SAd2[512];    // [(mt*2+kt)*64+lane]: A-frag of d2^T
  __shared__ half8 SAg1[512];    // A-frag of g1^T
  __shared__ half8 SBg2[512];    // [(kt*4+nt)*64+lane]: B-frag of g2 (normal)
  __shared__ float4 Srb[32];     // [s*16 + mt*4 + q]: s=0 d2b, s=1 g1b (row-indexed)
  const int tid = threadIdx.x;
  {
    if (tid < 256){
      int lane = tid & 63, mt = tid >> 6;
      int qq = (lane >> 4) & 3, m = lane & 15;
      half8 v;
      #pragma unroll
      for (int j = 0; j < 8; j++){
        int k = 8*qq + j;
        float x = 0.f;
        if (k < 3)      x = d1w[k*64 + 16*mt + m];
        else if (k == 3) x = d1b[16*mt + m];     // bias folded into K-pad row
        v[j] = (_Float16)x;
      }
      SAd1[tid] = v;
    }
    for (int i = tid; i < 512; i += 256){
      int lane = i & 63, mtkt = i >> 6;
      int mt = mtkt >> 1, kt = mtkt & 1;
      int qq = (lane >> 4) & 3, m = lane & 15;
      half8 v2, v1;
      #pragma unroll
      for (int j = 0; j < 8; j++){
        int k = 32*kt + 8*qq + j;
        v2[j] = (_Float16)d2w[k*64 + 16*mt + m];
        v1[j] = (_Float16)g1w[k*64 + 16*mt + m];
      }
      SAd2[i] = v2; SAg1[i] = v1;
    }
    fill_w64(SBg2, g2w, tid);
    if (tid < 32){
      int s = tid >> 4, mtq = tid & 15;
      const float* bp = s ? g1b : d2b;
      Srb[tid] = *(const float4*)&bp[4*mtq];
    }
  }
  __syncthreads();

  const int lane = tid & 63, wv = tid >> 6, q = lane >> 4, m16 = lane & 15;
  const floatx4 z4 = {0.f, 0.f, 0.f, 0.f};
  const float SC = 0.18033688f;   // (1/sqrt(64)) * log2(e)

  // identity B-frags for the MFMA-based frag->C transpose of W
  half8 Bid0, Bid1;
  #pragma unroll
  for (int j = 0; j < 8; j++){
    Bid0[j] = (_Float16)((8*q + j) == m16      ? 1.f : 0.f);
    Bid1[j] = (_Float16)((8*q + j) == m16 + 16 ? 1.f : 0.f);
  }
  float bg2c[4];
  #pragma unroll
  for (int nt = 0; nt < 4; nt++) bg2c[nt] = g2b[16*nt + m16];

  const int base = blockIdx.x*(4*PPW) + wv*PPW;
  const int bb   = (base >> 13) << 13;          // batch row base (N=8192)
  int idxs[PPW];
  #pragma unroll
  for (int p = 0; p < PPW; p++) idxs[p] = knn[(base + p)*KNN_ + m16];

  const int ia  = (((2*q) & 3) << 4) | m16;     // regroup source lanes
  const int ib  = (((2*q + 1) & 3) << 4) | m16;
  const int sel = q >> 1;

  #pragma unroll 2
  for (int p = 0; p < PPW; p++){
    const int gpt  = base + p;
    const int grow = bb + idxs[p];

    // gathers (frag layout = contiguous 16B row segments)
    const half8 Ka0 = *(const half8*)&kws[grow*64 + q*8];
    const half8 Ka1 = *(const half8*)&kws[grow*64 + 32 + q*8];
    const half8 Va0 = *(const half8*)&vws[grow*64 + q*8];
    const half8 Va1 = *(const half8*)&vws[grow*64 + 32 + q*8];
    const half8 Qb0 = *(const half8*)&qws[gpt*64 + q*8];
    const half8 Qb1 = *(const half8*)&qws[gpt*64 + 32 + q*8];

    // rel^T B-frag (+ constant-1 bias row at k=3)
    half8 Ar;
    #pragma unroll
    for (int j = 0; j < 8; j++) Ar[j] = (_Float16)0.0f;
    if (q == 0){
      #pragma unroll
      for (int j = 0; j < 3; j++)
        Ar[j] = (_Float16)(xyz[gpt*3 + j] - xyz[grow*3 + j]);
      Ar[3] = (_Float16)1.0f;
    }

    int pk[4][2];
    // S1 (transposed): T^T = d1^T @ rel^T (+bias via k=3), relu
    #pragma unroll
    for (int mt = 0; mt < 4; mt++){
      floatx4 acc = MFMA16(SAd1[mt*64 + lane], Ar, z4);
      pk[mt][0] = pk2f(fmaxf(acc[0], 0.f), fmaxf(acc[1], 0.f));
      pk[mt][1] = pk2f(fmaxf(acc[2], 0.f), fmaxf(acc[3], 0.f));
    }
    half8 Tf[2]; regroup(pk, Tf, ia, ib, sel);

    // S2 (transposed): P^T = d2^T @ T^T + bias
    #pragma unroll
    for (int mt = 0; mt < 4; mt++){
      floatx4 acc = MFMA16(SAd2[(mt*2 + 0)*64 + lane], Tf[0], z4);
      acc = MFMA16(SAd2[(mt*2 + 1)*64 + lane], Tf[1], acc);
      float4 rb = Srb[mt*4 + q];
      pk[mt][0] = pk2f(acc[0] + rb.x, acc[1] + rb.y);
      pk[mt][1] = pk2f(acc[2] + rb.z, acc[3] + rb.w);
    }
    half8 Pf[2]; regroup(pk, Pf, ia, ib, sel);

    // H = q - k + P (frag layout, packed f16)
    const half8 Hf0 = Qb0 - Ka0 + Pf[0];
    const half8 Hf1 = Qb1 - Ka1 + Pf[1];

    // S3 (transposed): U^T = g1^T @ H^T + bias, relu
    #pragma unroll
    for (int mt = 0; mt < 4; mt++){
      floatx4 acc = MFMA16(SAg1[(mt*2 + 0)*64 + lane], Hf0, z4);
      acc = MFMA16(SAg1[(mt*2 + 1)*64 + lane], Hf1, acc);
      float4 rb = Srb[16 + mt*4 + q];
      pk[mt][0] = pk2f(fmaxf(acc[0] + rb.x, 0.f), fmaxf(acc[1] + rb.y, 0.f));
      pk[mt][1] = pk2f(fmaxf(acc[2] + rb.z, 0.f), fmaxf(acc[3] + rb.w, 0.f));
    }
    half8 Uf[2]; regroup(pk, Uf, ia, ib, sel);

    // S4 (normal): logits = U @ g2 + bias  (C layout: rows=neighbors 4q+r)
    float A2[4][4];
    #pragma unroll
    for (int nt = 0; nt < 4; nt++){
      floatx4 acc = MFMA16(Uf[0], SBg2[nt*64 + lane], z4);
      acc = MFMA16(Uf[1], SBg2[(4 + nt)*64 + lane], acc);
      #pragma unroll
      for (int r = 0; r < 4; r++) A2[nt][r] = acc[r] + bg2c[nt];
    }

    // softmax over the 16 neighbors: local 4 rows + shfl_xor(16,32)
    float attnv[4][4];
    #pragma unroll
    for (int nt = 0; nt < 4; nt++){
      float mx = fmaxf(fmaxf(A2[nt][0], A2[nt][1]), fmaxf(A2[nt][2], A2[nt][3]));
      mx = fmaxf(mx, __shfl_xor(mx, 16));
      mx = fmaxf(mx, __shfl_xor(mx, 32));
      float s = 0.f;
      #pragma unroll
      for (int r = 0; r < 4; r++){
        float e = exp2f((A2[nt][r] - mx)*SC);
        attnv[nt][r] = e; s += e;
      }
      s += __shfl_xor(s, 16);
      s += __shfl_xor(s, 32);
      const float inv = 1.0f / s;
      #pragma unroll
      for (int r = 0; r < 4; r++) attnv[nt][r] *= inv;
    }

    // attn_out store (f32) direct from C-layout: coalesced dword stores
    float* ap = attn_out + (size_t)gpt*1024 + q*256 + m16;
    #pragma unroll
    for (int nt = 0; nt < 4; nt++)
      #pragma unroll
      for (int r = 0; r < 4; r++)
        ap[r*64 + nt*16] = attnv[nt][r];

    // res0 = sum_n attn * (v + pos_enc): W in frag layout -> C layout via identity MFMA
    const half8 Wf0 = Va0 + Pf[0];
    const half8 Wf1 = Va1 + Pf[1];
    float s4[4];
    #pragma unroll
    for (int nt = 0; nt < 4; nt++){
      floatx4 wc = MFMA16((nt < 2 ? Wf0 : Wf1), ((nt & 1) ? Bid1 : Bid0), z4);
      float sv = attnv[nt][0]*wc[0] + attnv[nt][1]*wc[1]
               + attnv[nt][2]*wc[2] + attnv[nt][3]*wc[3];
      sv += __shfl_xor(sv, 16);
      sv += __shfl_xor(sv, 32);
      s4[nt] = sv;
    }
    // lane (q,m16) stores feature 16q+m16
    float sq = (q & 1) ? ((q & 2) ? s4[3] : s4[1]) : ((q & 2) ? s4[2] : s4[0]);
    r0[gpt*64 + q*16 + m16] = (_Float16)sq;
  }
}

// ---------------- kernel 3: res = res0 @ fc2 + fc2_b + features (LDS-free) ----------------
__global__ __launch_bounds__(256, 4) void k3_fc2(
    const _Float16* __restrict__ r0, const float* __restrict__ fc2w,
    const float* __restrict__ fc2b, const float* __restrict__ feat,
    float* __restrict__ out_res)
{
  const int tid = threadIdx.x;
  const int wave = tid >> 6, lane = tid & 63, quad = lane >> 4, m16 = lane & 15;
  const int rowbase = blockIdx.x*64 + wave*16;

  half8 S[2][4];
  #pragma unroll
  for (int kt = 0; kt < 2; kt++)
    #pragma unroll
    for (int nt = 0; nt < 4; nt++)
      S[kt][nt] = wfrag(fc2w, kt*32 + quad*8, nt*16 + m16);

  float fb[4];
  #pragma unroll
  for (int nt = 0; nt < 4; nt++) fb[nt] = fc2b[nt*16 + m16];

  const half8 A0 = *(const half8*)&r0[(rowbase + m16)*64 + quad*8];
  const half8 A1 = *(const half8*)&r0[(rowbase + m16)*64 + 32 + quad*8];
  const floatx4 z4 = {0.f, 0.f, 0.f, 0.f};

  #pragma unroll
  for (int nt = 0; nt < 4; nt++){
    floatx4 acc = MFMA16(A0, S[0][nt], z4);
    acc = MFMA16(A1, S[1][nt], acc);
    #pragma unroll
    for (int r = 0; r < 4; r++){
      const int rowg = rowbase + quad*4 + r;
      const int col  = nt*16 + m16;
      out_res[rowg*64 + col] = acc[r] + fb[nt] + feat[rowg*64 + col];
    }
  }
}

extern "C" void kernel_launch(void* const* d_in, const int* in_sizes, int n_in,
                              void* d_out, int out_size, void* d_ws, size_t ws_size,
                              hipStream_t stream)
{
  (void)in_sizes; (void)n_in; (void)out_size; (void)ws_size;
  const float* xyz  = (const float*)d_in[0];
  const float* feat = (const float*)d_in[1];
  const int*   knn  = (const int*)d_in[2];
  const float* fc1w = (const float*)d_in[3];
  const float* fc1b = (const float*)d_in[4];
  const float* fc2w = (const float*)d_in[5];
  const float* fc2b = (const float*)d_in[6];
  const float* d1w  = (const float*)d_in[7];
  const float* d1b  = (const float*)d_in[8];
  const float* d2w  = (const float*)d_in[9];
  const float* d2b  = (const float*)d_in[10];
  const float* g1w  = (const float*)d_in[11];
  const float* g1b  = (const float*)d_in[12];
  const float* g2w  = (const float*)d_in[13];
  const float* g2b  = (const float*)d_in[14];
  const float* wq   = (const float*)d_in[15];
  const float* wk   = (const float*)d_in[16];
  const float* wv   = (const float*)d_in[17];

  _Float16* ws  = (_Float16*)d_ws;
  _Float16* qws = ws;                      // TOT*64 halfs
  _Float16* kws = ws + (size_t)TOT*64;
  _Float16* vws = ws + (size_t)2*TOT*64;
  _Float16* r0  = ws + (size_t)3*TOT*64;

  float* out      = (float*)d_out;
  float* out_res  = out;                     // (B,N,64)
  float* out_attn = out + (size_t)TOT*64;    // (B,N,K,64)

  k1_qkv<<<TOT/64, 256, 0, stream>>>(feat, fc1w, fc1b, wq, wk, wv, qws, kws, vws);
  k2_point<<<TOT/(4*PPW), 256, 0, stream>>>(xyz, knn, d1w, d1b, d2w, d2b,
                                            g1w, g1b, g2w, g2b,
                                            qws, kws, vws, r0, out_attn);
  k3_fc2<<<TOT/64, 256, 0, stream>>>(r0, fc2w, fc2b, feat, out_res);
}